// Round 10
// baseline (171.733 us; speedup 1.0000x reference)
//
#include <hip/hip_runtime.h>
#include <stdint.h>

#define EPS_F 1e-7f

typedef float f32x4 __attribute__((ext_vector_type(4)));

union A8 { uint2 u2; long l; };

__device__ __forceinline__ unsigned cvt4(float a, float b, float c, float d) {
  int v = __builtin_amdgcn_cvt_pk_fp8_f32(a, b, 0, false);   // bytes 0,1
  return (unsigned)__builtin_amdgcn_cvt_pk_fp8_f32(c, d, v, true);  // bytes 2,3
}

// ---------------------------------------------------------------------------
// prep: prototypes fp32 (2048x512) -> fp8 e4m3 in MFMA B-fragment order for
// 16x16x32 fp8.  16-B chunk (g,kp2), lane l (q=l>>4, cl=l&15) holds
// col n = 16g + cl;  bytes[0:8) = k [64*kp2 + 8q, +8)         (even K32-step)
//                    bytes[8:16) = k [64*kp2 + 32 + 8q, +8)   (odd  K32-step)
// Also y2[c] (fp32 exact), ry[c] = 1/(1-y2) (clamp never binds: points lie
// inside the radius-0.8 ball -> 1-y2 >= 0.36), and out = 0.
// ---------------------------------------------------------------------------
__global__ __launch_bounds__(256) void prep_kernel(
    const float* __restrict__ protos, uint8_t* __restrict__ wsB,
    float* __restrict__ y2a, float* __restrict__ rya,
    float* __restrict__ out) {
  const int lane = threadIdx.x & 63;
  const int w    = threadIdx.x >> 6;
  const int kp2  = lane >> 2, q = lane & 3;   // writer coords (lanes 0..31)
  const int sl0  = 8 * kp2 + q;               // source lane of even half
  const int sl1  = sl0 + 4;                   // source lane of odd half
#pragma unroll
  for (int i = 0; i < 4; ++i) {
    int c = (blockIdx.x * 4 + w) * 4 + i;
    const float4* p = (const float4*)(protos + (size_t)c * 512 + lane * 8);
    float4 f0 = p[0], f1 = p[1];
    float s = f0.x*f0.x + f0.y*f0.y + f0.z*f0.z + f0.w*f0.w
            + f1.x*f1.x + f1.y*f1.y + f1.z*f1.z + f1.w*f1.w;
#pragma unroll
    for (int off = 32; off > 0; off >>= 1) s += __shfl_xor(s, off, 64);
    if (lane == 0) { y2a[c] = s; rya[c] = 1.f / (1.f - s); }
    unsigned ux = cvt4(f0.x, f0.y, f0.z, f0.w);   // this lane's k [8l, 8l+4)
    unsigned uy = cvt4(f1.x, f1.y, f1.z, f1.w);   // k [8l+4, 8l+8)
    uint4 ch;
    ch.x = __shfl((int)ux, sl0, 64);
    ch.y = __shfl((int)uy, sl0, 64);
    ch.z = __shfl((int)ux, sl1, 64);
    ch.w = __shfl((int)uy, sl1, 64);
    if (lane < 32) {
      int g = c >> 4, cl = c & 15;
      ((uint4*)wsB)[((size_t)g * 8 + kp2) * 64 + q * 16 + cl] = ch;
    }
  }
  if (blockIdx.x == 0 && threadIdx.x == 0) out[0] = 0.f;
}

// ---------------------------------------------------------------------------
// gemm_min: 512 blocks x 256 thr (4 waves), launch_bounds(256,2).
// LDS-BW analysis (r5-r9 post-mortem): with cf=2, 4 ds_read_b128/kp (48 cyc
// of the CU's single LDS pipe) vs 74 matrix cyc/SIMD -> 8 waves demand 384
// LDS cyc per 148 matrix cyc = 2.6x oversubscribed -> MfmaUtil capped ~38%
// (measured 34%).  cf=4 doubles MFMAs per A-read: 384 LDS vs 592 matrix ->
// matrix-bound.  Floors per CU: LDS 10.3 us, matrix 33.5 us.
//   - A: 64 rows x 512 K fp8 staged ONCE into 32 KB LDS in A-fragment order;
//     x2 fp32-exact in the staging pass.  ONE barrier before the reduction.
//   - B: wave w owns cols [w*512,+512) as 8 strips of 64 (4 col-frags);
//     chunk base w*256 (r5-r8 used w*128: overlapping columns with
//     mismatched y2 -- masked only because the loss is identically 0).
//     Register pipeline depth 2 kp-steps (8 b128 in flight, ~300 cyc cover).
//   - per kp: 4 ds_read_b128 (A) + 4 global b128 (B) + 32 MFMAs.
//   - epilogue per strip: tmin = min(tmin, max(x2+y2-2dot,0)*ry); 1/(1-x2)
//     folded once per row at the end (monotone); in-block min -> acosh/relu,
//     one atomicAdd per block.
// ---------------------------------------------------------------------------
__global__ __launch_bounds__(256, 2) void gemm_min_kernel(
    const float* __restrict__ z, const uint8_t* __restrict__ wsB,
    const float* __restrict__ y2a, const float* __restrict__ rya,
    const float* __restrict__ marg, float* __restrict__ out) {
  __shared__ uint8_t As[32 * 1024];   // 32 chunks (kp2*4 + rf) x 64 lanes x 16B
  __shared__ float x2s[64];
  __shared__ float minbuf[64][4];

  const int tid  = threadIdx.x;
  const int lane = tid & 63;
  const int w    = tid >> 6;          // wave 0..3
  const int q    = lane >> 4;         // quad 0..3
  const int l15  = lane & 15;
  const size_t rowbase = (size_t)blockIdx.x * 64;

  // ---- A staging + fused x2: wave w owns rows w*16 + l15 ----
  {
    const float* rp0 = z + (rowbase + w * 16 + l15) * 512;
    float s = 0.f;
#pragma unroll
    for (int j = 0; j < 8; ++j) {
      const float* rp = rp0 + j * 64 + q * 8;
      float4 a0 = ((const float4*)rp)[0];
      float4 a1 = ((const float4*)rp)[1];
      float4 b0 = ((const float4*)(rp + 32))[0];
      float4 b1 = ((const float4*)(rp + 32))[1];
      s += a0.x*a0.x + a0.y*a0.y + a0.z*a0.z + a0.w*a0.w
         + a1.x*a1.x + a1.y*a1.y + a1.z*a1.z + a1.w*a1.w
         + b0.x*b0.x + b0.y*b0.y + b0.z*b0.z + b0.w*b0.w
         + b1.x*b1.x + b1.y*b1.y + b1.z*b1.z + b1.w*b1.w;
      uint4 ch;
      ch.x = cvt4(a0.x, a0.y, a0.z, a0.w);
      ch.y = cvt4(a1.x, a1.y, a1.z, a1.w);
      ch.z = cvt4(b0.x, b0.y, b0.z, b0.w);
      ch.w = cvt4(b1.x, b1.y, b1.z, b1.w);
      ((uint4*)As)[(j * 4 + w) * 64 + lane] = ch;   // chunk = kp2*4 + rf(=w)
    }
    s += __shfl_xor(s, 16, 64);
    s += __shfl_xor(s, 32, 64);      // sum over the 4 q-lanes of this row
    if (lane < 16) x2s[w * 16 + lane] = s;
  }
  __syncthreads();  // the ONLY barrier before the final reduction

  // x2 resident per lane: rows rf*16 + q*4 + r
  float x2r[4][4];
#pragma unroll
  for (int rf = 0; rf < 4; ++rf) {
    float4 x4 = *(const float4*)&x2s[rf * 16 + q * 4];
    x2r[rf][0] = x4.x; x2r[rf][1] = x4.y; x2r[rf][2] = x4.z; x2r[rf][3] = x4.w;
  }

  const uint4* Ap = (const uint4*)As;
  // wave's B base: groups [w*32, +32) -> chunks [w*256, +256).
  // strip s, col-frag cf, kp2: relative chunk = (s*4 + cf)*8 + kp2.
  const uint4* Bgw = (const uint4*)wsB + ((size_t)w * 256) * 64 + lane;

  // B pipeline: bank = kp2&1, prefetch kp2+2 into the bank being freed.
  uint4 Bw[2][4];
#pragma unroll
  for (int sl = 0; sl < 2; ++sl)
#pragma unroll
    for (int cf = 0; cf < 4; ++cf)
      Bw[sl][cf] = Bgw[(size_t)(cf * 8 + sl) * 64];

  float tmin[4][4];
#pragma unroll
  for (int rf = 0; rf < 4; ++rf)
#pragma unroll
    for (int r = 0; r < 4; ++r) tmin[rf][r] = 3.4e38f;

  const float* y2p = y2a + w * 512 + l15;
  const float* ryp = rya + w * 512 + l15;

#pragma clang loop unroll(disable)
  for (int s = 0; s < 8; ++s) {
    f32x4 acc[4][4];
#pragma unroll
    for (int rf = 0; rf < 4; ++rf)
#pragma unroll
      for (int cf = 0; cf < 4; ++cf) {
        f32x4 z4 = {0.f, 0.f, 0.f, 0.f};
        acc[rf][cf] = z4;
      }
    float y2v[4], ryv[4];
#pragma unroll
    for (int cf = 0; cf < 4; ++cf) {
      y2v[cf] = y2p[s * 64 + cf * 16];
      ryv[cf] = ryp[s * 64 + cf * 16];
    }

#pragma unroll
    for (int kp2 = 0; kp2 < 8; ++kp2) {
      const int sl = kp2 & 1;
      uint4 bu[4];
#pragma unroll
      for (int cf = 0; cf < 4; ++cf) bu[cf] = Bw[sl][cf];
      {  // prefetch kp-step +2 into the just-freed bank (pad absorbs tail)
        int ip = s * 8 + kp2 + 2;
        int sp = ip >> 3, kq = ip & 7;
#pragma unroll
        for (int cf = 0; cf < 4; ++cf)
          Bw[sl][cf] = Bgw[(size_t)((sp * 4 + cf) * 8 + kq) * 64];
      }
#pragma unroll
      for (int rf = 0; rf < 4; ++rf) {
        uint4 av = Ap[(kp2 * 4 + rf) * 64 + lane];
        A8 alo, ahi;
        alo.u2 = make_uint2(av.x, av.y);
        ahi.u2 = make_uint2(av.z, av.w);
#pragma unroll
        for (int cf = 0; cf < 4; ++cf) {
          A8 blo, bhi;
          blo.u2 = make_uint2(bu[cf].x, bu[cf].y);
          bhi.u2 = make_uint2(bu[cf].z, bu[cf].w);
          acc[rf][cf] = __builtin_amdgcn_mfma_f32_16x16x32_fp8_fp8(
              alo.l, blo.l, acc[rf][cf], 0, 0, 0);
          acc[rf][cf] = __builtin_amdgcn_mfma_f32_16x16x32_fp8_fp8(
              ahi.l, bhi.l, acc[rf][cf], 0, 0, 0);
        }
      }
    }

    // epilogue: cols c = w*512 + s*64 + cf*16 + l15
#pragma unroll
    for (int rf = 0; rf < 4; ++rf) {
#pragma unroll
      for (int r = 0; r < 4; ++r) {
        float xv = x2r[rf][r];
        float m01, m23;
        {
          float u0 = fmaxf(fmaf(-2.f, acc[rf][0][r], xv + y2v[0]), 0.f) * ryv[0];
          float u1 = fmaxf(fmaf(-2.f, acc[rf][1][r], xv + y2v[1]), 0.f) * ryv[1];
          m01 = fminf(u0, u1);
        }
        {
          float u2 = fmaxf(fmaf(-2.f, acc[rf][2][r], xv + y2v[2]), 0.f) * ryv[2];
          float u3 = fmaxf(fmaf(-2.f, acc[rf][3][r], xv + y2v[3]), 0.f) * ryv[3];
          m23 = fminf(u2, u3);
        }
        tmin[rf][r] = fminf(tmin[rf][r], fminf(m01, m23));
      }
    }
  }

  // ---- min across the 16 lanes (l15) sharing each row ----
#pragma unroll
  for (int rf = 0; rf < 4; ++rf) {
#pragma unroll
    for (int r = 0; r < 4; ++r) {
      float v = tmin[rf][r];
      v = fminf(v, __shfl_xor(v, 1, 64));
      v = fminf(v, __shfl_xor(v, 2, 64));
      v = fminf(v, __shfl_xor(v, 4, 64));
      v = fminf(v, __shfl_xor(v, 8, 64));
      if (l15 == 0) minbuf[rf * 16 + q * 4 + r][w] = v;  // row = q*4 + r
    }
  }
  __syncthreads();

  if (w == 0) {  // lane = row 0..63
    float m = fminf(fminf(minbuf[lane][0], minbuf[lane][1]),
                    fminf(minbuf[lane][2], minbuf[lane][3]));
    float t = m / (1.f - x2s[lane]);         // fold 1/(1-x2) once per row
    float arg = fmaxf(fmaf(2.f, t, 1.f), 1.f + EPS_F);
    float contrib = fmaxf(marg[0] - acoshf(arg), 0.f);
#pragma unroll
    for (int off = 32; off > 0; off >>= 1) contrib += __shfl_xor(contrib, off, 64);
    if (lane == 0) atomicAdd(out, contrib * (1.0f / 32768.f));
  }
}

// ---------------------------------------------------------------------------
extern "C" void kernel_launch(void* const* d_in, const int* in_sizes, int n_in,
                              void* d_out, int out_size, void* d_ws, size_t ws_size,
                              hipStream_t stream) {
  const float* z      = (const float*)d_in[0];  // 32768 x 512 fp32
  const float* protos = (const float*)d_in[1];  // 2048 x 512 fp32
  const float* marg   = (const float*)d_in[2];  // scalar
  float* out = (float*)d_out;
  uint8_t* wsB = (uint8_t*)d_ws;                                 // 1 MB image
  // 192 KB pad absorbs the harmless B-pipeline tail over-reads (<= 70 KB).
  char* p = (char*)d_ws + (1 << 20) + 192 * 1024;
  float* y2a = (float*)p;                 p += 8 * 1024;         // 2048 f32
  float* rya = (float*)p;                                        // 2048 f32

  prep_kernel<<<128, 256, 0, stream>>>(protos, wsB, y2a, rya, out);
  gemm_min_kernel<<<512, 256, 0, stream>>>(z, wsB, y2a, rya, marg, out);
}